// Round 4
// baseline (328.712 us; speedup 1.0000x reference)
//
#include <hip/hip_runtime.h>
#include <hip/hip_bf16.h>
#include <stdint.h>

typedef __bf16 bf16;
typedef __bf16 bf16x4 __attribute__((ext_vector_type(4)));
typedef __bf16 bf16x8 __attribute__((ext_vector_type(8)));
typedef float f32x4 __attribute__((ext_vector_type(4)));
typedef float f32x8 __attribute__((ext_vector_type(8)));

#define MFMA16 __builtin_amdgcn_mfma_f32_16x16x32_bf16

// async global->LDS, 16B per lane; LDS dest must be base + lane*16 pattern.
__device__ __forceinline__ void gload_lds16(void* lds, const void* g) {
  __builtin_amdgcn_global_load_lds(
      (const __attribute__((address_space(1))) unsigned int*)g,
      (__attribute__((address_space(3))) unsigned int*)lds, 16, 0, 0);
}

#define S_BARRIER() __builtin_amdgcn_s_barrier()
// rule #18: sched_barrier(0) right after an inline-asm lgkmcnt wait so MFMAs
// can't be hoisted above it.
#define WAIT_LGKM0()                                   \
  do {                                                 \
    asm volatile("s_waitcnt lgkmcnt(0)" ::: "memory"); \
    __builtin_amdgcn_sched_barrier(0);                 \
  } while (0)
#define WAIT_VM(n) asm volatile("s_waitcnt vmcnt(" #n ")" ::: "memory")

// ---------------------------------------------------------------------------
// fp32 -> bf16 converts (HBM-bound)
// ---------------------------------------------------------------------------
__global__ __launch_bounds__(256) void cvt3(
    const float* __restrict__ s0, const float* __restrict__ s1,
    const float* __restrict__ s2, bf16* __restrict__ d0,
    bf16* __restrict__ d1, bf16* __restrict__ d2) {
  const float* srcs[3] = {s0, s1, s2};
  bf16* dsts[3] = {d0, d1, d2};
  const float* src = srcs[blockIdx.y];
  bf16* dst = dsts[blockIdx.y];
  int i = (blockIdx.x * 256 + threadIdx.x) * 4;
  f32x4 v = *(const f32x4*)(src + i);
  bf16x4 o;
#pragma unroll
  for (int j = 0; j < 4; j++) o[j] = (bf16)v[j];
  *(bf16x4*)(dst + i) = o;
}

__global__ __launch_bounds__(256) void cvt1(const float* __restrict__ src,
                                            bf16* __restrict__ dst) {
  int i = (blockIdx.x * 256 + threadIdx.x) * 4;
  f32x4 v = *(const f32x4*)(src + i);
  bf16x4 o;
#pragma unroll
  for (int j = 0; j < 4; j++) o[j] = (bf16)v[j];
  *(bf16x4*)(dst + i) = o;
}

__global__ __launch_bounds__(256) void cvt4(const float* __restrict__ w0,
                                            const float* __restrict__ w1,
                                            const float* __restrict__ w2,
                                            const float* __restrict__ w3,
                                            bf16* __restrict__ dst) {
  const float* srcs[4] = {w0, w1, w2, w3};
  const float* src = srcs[blockIdx.y];
  int i = (blockIdx.x * 256 + threadIdx.x) * 4;
  f32x4 v = *(const f32x4*)(src + i);
  bf16x4 o;
#pragma unroll
  for (int j = 0; j < 4; j++) o[j] = (bf16)v[j];
  *(bf16x4*)(dst + (size_t)blockIdx.y * 1048576 + i) = o;
}

// ---------------------------------------------------------------------------
// 128x256 fine-grained pipelined GEMM, K = 1024 fixed (16 K-tiles of 64).
// (verified R3: passed; gemm_qkv no longer in top-5.) Body unchanged.
// ---------------------------------------------------------------------------
__device__ __forceinline__ void gemmF_body(const bf16* __restrict__ A,
                                           const bf16* __restrict__ W,
                                           void* __restrict__ Craw, int mode,
                                           int m0, int n0, bf16* smem) {
  constexpr int K = 1024;
  const int t = threadIdx.x;
  const int lane = t & 63;
  const int m16 = lane & 15;
  const int quad = (lane >> 4) & 3;
  const int sw = m16 & 7;  // row&7 for frag reads (row offsets are 16-mult)
  const int w = t >> 6;
  const int wm = (w >> 2) * 64;  // wave M offset (2 wave-rows)
  const int wn = (w & 3) * 64;   // wave N offset (4 wave-cols)

  const bf16* Ab = A + (size_t)m0 * K;
  const bf16* Bb = W + (size_t)n0 * K;

  // stage K-tile kt into buf: A 128x64 (2 rounds) + B 256x64 (4 rounds).
  auto STG = [&](int buf, int kt) {
    bf16* dA = smem + buf * 24576;
    bf16* dB = dA + 8192;
    const bf16* sA = Ab + kt * 64;
    const bf16* sB = Bb + kt * 64;
#pragma unroll
    for (int ld = 0; ld < 2; ld++) {
      int idx = ld * 512 + t;
      int row = idx >> 3;
      int c = (idx & 7) ^ (row & 7);  // pre-swizzled global chunk
      gload_lds16(dA + idx * 8, sA + (size_t)row * K + c * 8);
    }
#pragma unroll
    for (int ld = 0; ld < 4; ld++) {
      int idx = ld * 512 + t;
      int row = idx >> 3;
      int c = (idx & 7) ^ (row & 7);
      gload_lds16(dB + idx * 8, sB + (size_t)row * K + c * 8);
    }
  };

  bf16x8 aR[8], bR[8];
  auto LD = [&](int buf) {
    const bf16* As = smem + buf * 24576;
    const bf16* Bs = As + 8192;
#pragma unroll
    for (int f = 0; f < 4; f++)
#pragma unroll
      for (int ks = 0; ks < 2; ks++) {
        aR[f * 2 + ks] = *(const bf16x8*)&As[(wm + f * 16 + m16) * 64 +
                                             (((ks * 4 + quad) ^ sw) * 8)];
        bR[f * 2 + ks] = *(const bf16x8*)&Bs[(wn + f * 16 + m16) * 64 +
                                             (((ks * 4 + quad) ^ sw) * 8)];
      }
  };

  f32x4 acc[4][4];
#pragma unroll
  for (int f = 0; f < 4; f++)
#pragma unroll
    for (int g = 0; g < 4; g++) acc[f][g] = (f32x4){0.f, 0.f, 0.f, 0.f};

  auto MM = [&]() {
    __builtin_amdgcn_s_setprio(1);
#pragma unroll
    for (int f = 0; f < 4; f++)
#pragma unroll
      for (int g = 0; g < 4; g++)
#pragma unroll
        for (int ks = 0; ks < 2; ks++)
          acc[f][g] = MFMA16(aR[f * 2 + ks], bR[g * 2 + ks], acc[f][g], 0, 0, 0);
    __builtin_amdgcn_s_setprio(0);
  };

  // ---- prologue: stage tiles 0,1; retire tile0 (vmcnt leaves tile1's 6).
  STG(0, 0);
  STG(1, 1);
  WAIT_VM(6);
  S_BARRIER();

  int bufR = 0;
#pragma unroll 1
  for (int kt = 0; kt < 14; ++kt) {
    LD(bufR);
    int bufS = bufR + 2;
    if (bufS >= 3) bufS -= 3;
    STG(bufS, kt + 2);
    S_BARRIER();
    WAIT_LGKM0();
    MM();
    WAIT_VM(6);  // retires tile (kt+1)'s 6 loads; leaves tile (kt+2)'s
    S_BARRIER();
    bufR = (bufR + 1 == 3) ? 0 : bufR + 1;
  }
  // ---- phase 14: no stage; drain tile15 fully.
  LD(bufR);
  S_BARRIER();
  WAIT_LGKM0();
  MM();
  WAIT_VM(0);
  S_BARRIER();
  bufR = (bufR + 1 == 3) ? 0 : bufR + 1;
  // ---- phase 15: last tile.
  LD(bufR);
  S_BARRIER();
  WAIT_LGKM0();
  MM();

  // ---- epilogue
#pragma unroll
  for (int f = 0; f < 4; f++) {
    int rbase = m0 + wm + f * 16 + quad * 4;
#pragma unroll
    for (int g = 0; g < 4; g++) {
      int col = n0 + wn + g * 16 + m16;
#pragma unroll
      for (int r = 0; r < 4; r++) {
        int row = rbase + r;
        if (mode == 0) {
          ((float*)Craw)[(size_t)row * 1024 + col] = acc[f][g][r];
        } else {
          int b = row >> 11, s = row & 2047;
          int h = col >> 6, d = col & 63;
          bf16 v = (bf16)acc[f][g][r];
          if (mode == 1)
            ((bf16*)Craw)[(((size_t)(b * 16 + h)) * 2048 + s) * 64 + d] = v;
          else
            ((bf16*)Craw)[(((size_t)(b * 16 + h)) * 64 + d) * 2048 + s] = v;
        }
      }
    }
  }
}

// Fused Q/K/V projections: grid (4, 64, 3), 512 thr.
__global__ __launch_bounds__(512, 2) void gemm_qkv(
    const bf16* __restrict__ xq, const bf16* __restrict__ xk,
    const bf16* __restrict__ xv, const bf16* __restrict__ wb,
    const int* __restrict__ vlen, bf16* __restrict__ qp,
    bf16* __restrict__ kp, bf16* __restrict__ vt) {
  __shared__ bf16 smem[73728];  // 144 KiB
  const int m0 = blockIdx.y * 128;
  const int n0 = blockIdx.x * 256;
  const int z = blockIdx.z;
  if (z >= 1) {  // K/V: skip fully-masked s-strips (block-uniform)
    int b = m0 >> 11;
    int s0 = m0 & 2047;
    int vl = vlen[b];
    if (vl != 0 && s0 >= vl) return;
  }
  const bf16* A = (z == 0) ? xq : (z == 1) ? xk : xv;
  const bf16* W = wb + (size_t)z * 1048576;
  bf16* C = (z == 0) ? qp : (z == 1) ? kp : vt;
  gemmF_body(A, W, C, (z == 2) ? 2 : 1, m0, n0, smem);
}

// Single GEMM (bf16 inputs): grid (4, 64) = 256 items = one perfect round.
__global__ __launch_bounds__(512, 2) void gemm_one(const bf16* __restrict__ A,
                                                   const bf16* __restrict__ W,
                                                   void* __restrict__ Craw,
                                                   int mode) {
  __shared__ bf16 smem[73728];
  gemmF_body(A, W, Craw, mode, blockIdx.y * 128, blockIdx.x * 256, smem);
}

// Fallback GEMM with fp32 operands converted in staging (Tier C path).
template <int AF32, int WF32>
__global__ __launch_bounds__(256) void gemm_bt(const void* __restrict__ Araw,
                                               const void* __restrict__ Wraw,
                                               void* __restrict__ Craw,
                                               int mode) {
  constexpr int K = 1024;
  __shared__ bf16 As[128 * 32];
  __shared__ bf16 Bs[128 * 32];
  const int t = threadIdx.x;
  const int lane = t & 63;
  const int quad = lane >> 4;
  const int m16 = lane & 15;
  const int w = t >> 6;
  const int m0 = blockIdx.y * 128;
  const int n0 = blockIdx.x * 128;
  const int wm = (w >> 1) * 64;
  const int wn = (w & 1) * 64;

  f32x4 acc[4][4];
#pragma unroll
  for (int i = 0; i < 4; i++)
#pragma unroll
    for (int j = 0; j < 4; j++) acc[i][j] = (f32x4){0.f, 0.f, 0.f, 0.f};

  for (int kt = 0; kt < K / 32; kt++) {
    bf16x8 aR[2], bR[2];
#pragma unroll
    for (int p = 0; p < 2; p++) {
      int idx = p * 256 + t;
      int row = idx >> 2;
      int ce = (idx & 3) * 8;
      size_t aoff = (size_t)(m0 + row) * K + kt * 32 + ce;
      size_t boff = (size_t)(n0 + row) * K + kt * 32 + ce;
      if constexpr (AF32) {
        f32x8 av = *(const f32x8*)((const float*)Araw + aoff);
#pragma unroll
        for (int j = 0; j < 8; j++) aR[p][j] = (bf16)av[j];
      } else {
        aR[p] = *(const bf16x8*)((const bf16*)Araw + aoff);
      }
      if constexpr (WF32) {
        f32x8 bv = *(const f32x8*)((const float*)Wraw + boff);
#pragma unroll
        for (int j = 0; j < 8; j++) bR[p][j] = (bf16)bv[j];
      } else {
        bR[p] = *(const bf16x8*)((const bf16*)Wraw + boff);
      }
    }
    __syncthreads();
#pragma unroll
    for (int p = 0; p < 2; p++) {
      int idx = p * 256 + t;
      *(bf16x8*)&As[idx * 8] = aR[p];
      *(bf16x8*)&Bs[idx * 8] = bR[p];
    }
    __syncthreads();

    bf16x8 af[4], bfr[4];
#pragma unroll
    for (int i = 0; i < 4; i++) {
      af[i] = *(const bf16x8*)&As[(wm + i * 16 + m16) * 32 + quad * 8];
      bfr[i] = *(const bf16x8*)&Bs[(wn + i * 16 + m16) * 32 + quad * 8];
    }
#pragma unroll
    for (int i = 0; i < 4; i++)
#pragma unroll
      for (int j = 0; j < 4; j++)
        acc[i][j] = MFMA16(af[i], bfr[j], acc[i][j], 0, 0, 0);
  }

#pragma unroll
  for (int i = 0; i < 4; i++) {
    int rbase = m0 + wm + i * 16 + quad * 4;
#pragma unroll
    for (int j = 0; j < 4; j++) {
      int col = n0 + wn + j * 16 + m16;
#pragma unroll
      for (int r = 0; r < 4; r++) {
        int row = rbase + r;
        if (mode == 0) {
          ((float*)Craw)[(size_t)row * 1024 + col] = acc[i][j][r];
        } else {
          int b = row >> 11, s = row & 2047;
          int h = col >> 6, d = col & 63;
          bf16 v = (bf16)acc[i][j][r];
          if (mode == 1)
            ((bf16*)Craw)[(((size_t)(b * 16 + h)) * 2048 + s) * 64 + d] = v;
          else
            ((bf16*)Craw)[(((size_t)(b * 16 + h)) * 64 + d) * 2048 + s] = v;
        }
      }
    }
  }
}

// ---------------------------------------------------------------------------
// Flash attention, de-onlined softmax (fixed offset M=32):
//   p = exp(dot*0.125 - 32) = exp2(dot*0.18033688 - 46.166241)
// Masked keys: p = 0 exactly; vl==0: p = 1 (uniform softmax, matches ref).
// R4 restructure (R3 counters: VALUBusy 54 / Mfma 19 / occ 26 -> latency +
// staging bound, FETCH 78.9MB = K/V L2 thrash across XCDs):
//  - 8 waves, 256 q-rows/block, grid (8,64) = 512 blocks = 2/CU exact;
//    K/V staged once per 256 q (was 128) -> staging traffic halved.
//  - K/V double-buffered with counted vmcnt(2): stage kt+1 at top of iter
//    kt, loads get a full compute phase to land (was: barrier-drain of full
//    memory latency every kt). WAR: buf[(kt+1)&1] last read iter kt-1,
//    whose closing s_barrier precedes the stage.
//  - XCD head-colocation: xcd=id&7 serves 8 heads (<=4MB K/V ~ its L2).
// qp/kp: [B,H,S,64]. vt: [B,H,64,S]. XOR chunk swizzle both-sides.
// Ps: per-wave 32x64 P tile, row stride 72 elems (2-way banks = free).
// ---------------------------------------------------------------------------
__global__ __launch_bounds__(512, 4) void attn(const bf16* __restrict__ qp,
                                               const bf16* __restrict__ kp,
                                               const bf16* __restrict__ vt,
                                               const int* __restrict__ vlen,
                                               bf16* __restrict__ ctx) {
  __shared__ bf16 Ks[2][4096];   // 64 keys x 64 d, dbuf
  __shared__ bf16 Vs[2][4096];   // 64 d x 64 keys, dbuf
  __shared__ bf16 Ps[8 * 2304];  // per-wave 32x72

  const int t = threadIdx.x;
  const int lane = t & 63;
  const int quad = (lane >> 4) & 3;
  const int m16 = lane & 15;
  const int sw = m16 & 7;  // read-side XOR (row&7)
  const int w = t >> 6;    // 0..7
  // XCD head-colocation remap (perf heuristic: HW assigns xcd = id % 8).
  const int id = blockIdx.y * 8 + blockIdx.x;  // gridDim.x == 8
  const int xcd = id & 7;
  const int j = id >> 3;             // 0..63
  const int bh = (j >> 3) * 8 + xcd; // 8 heads per XCD, qt-adjacent in time
  const int qt = j & 7;
  const int b = bh >> 4;
  const int h = bh & 15;
  const int vl = vlen[b];

  const float C1 = 0.18033688f;  // 0.125 * log2(e)
  const float C2 = 46.166241f;   // 32 * log2(e)
  const float mArg = (vl == 0) ? 0.0f : -12800.0f;

  bf16x8 qf[2][2];
#pragma unroll
  for (int a = 0; a < 2; a++) {
    const bf16* qb =
        qp + ((size_t)(bh * 2048 + qt * 256 + w * 32 + a * 16 + m16)) * 64;
    qf[a][0] = *(const bf16x8*)(qb + quad * 8);
    qf[a][1] = *(const bf16x8*)(qb + 32 + quad * 8);
  }

  float rsum[2][4] = {{0.f, 0.f, 0.f, 0.f}, {0.f, 0.f, 0.f, 0.f}};
  f32x4 o[2][4];
#pragma unroll
  for (int a = 0; a < 2; a++)
#pragma unroll
    for (int nt = 0; nt < 4; nt++) o[a][nt] = (f32x4){0.f, 0.f, 0.f, 0.f};

  const int ktEnd = (vl == 0) ? 32 : ((vl + 63) >> 6);

  // stage K/V tile kt into buf: 512 thr x 1 gload each for K and V.
  const int srow = t >> 3;                 // 0..63
  const int sgc = (t & 7) ^ (srow & 7);    // XOR swizzle in global address
  auto STAGE = [&](int buf, int kt) {
    gload_lds16(&Ks[buf][t * 8],
                &kp[((size_t)(bh * 2048 + kt * 64 + srow)) * 64 + sgc * 8]);
    gload_lds16(&Vs[buf][t * 8],
                &vt[((size_t)(bh * 64 + srow)) * 2048 + kt * 64 + sgc * 8]);
  };

  STAGE(0, 0);

  for (int kt = 0; kt < ktEnd; kt++) {
    const int cur = kt & 1;
    if (kt + 1 < ktEnd) {
      STAGE(cur ^ 1, kt + 1);
      WAIT_VM(2);  // retires tile kt's 2 loads (per-wave FIFO); kt+1 in flight
    } else {
      WAIT_VM(0);
    }
    S_BARRIER();  // tile kt visible to all waves
    const bf16* Ksb = Ks[cur];
    const bf16* Vsb = Vs[cur];

    // ---- QK^T: 2 q-subtiles share each K fragment
    f32x4 s[2][4];
#pragma unroll
    for (int a = 0; a < 2; a++)
#pragma unroll
      for (int nt = 0; nt < 4; nt++) s[a][nt] = (f32x4){0.f, 0.f, 0.f, 0.f};
#pragma unroll
    for (int nt = 0; nt < 4; nt++) {
      int key = nt * 16 + m16;
#pragma unroll
      for (int ks = 0; ks < 2; ks++) {
        bf16x8 kf =
            *(const bf16x8*)&Ksb[key * 64 + (((ks * 4 + quad) ^ sw) * 8)];
        s[0][nt] = MFMA16(qf[0][ks], kf, s[0][nt], 0, 0, 0);
        s[1][nt] = MFMA16(qf[1][ks], kf, s[1][nt], 0, 0, 0);
      }
    }

    // ---- p = exp2(dot*C1 - C2); masked -> 0 (or 1 when vl==0)
#pragma unroll
    for (int nt = 0; nt < 4; nt++) {
      bool masked = (kt * 64 + nt * 16 + m16) >= vl;
#pragma unroll
      for (int a = 0; a < 2; a++)
#pragma unroll
        for (int r = 0; r < 4; r++) {
          float arg = masked ? mArg : (s[a][nt][r] * C1 - C2);
          bf16 pb = (bf16)__builtin_amdgcn_exp2f(arg);
          rsum[a][r] += (float)pb;
          Ps[w * 2304 + (a * 16 + quad * 4 + r) * 72 + nt * 16 + m16] = pb;
        }
    }

    // ---- PV: 2 q-subtiles share each V fragment (per-wave DS is in-order)
#pragma unroll
    for (int ks = 0; ks < 2; ks++) {
      bf16x8 pf0 = *(const bf16x8*)&Ps[w * 2304 + m16 * 72 + ks * 32 + quad * 8];
      bf16x8 pf1 =
          *(const bf16x8*)&Ps[w * 2304 + (16 + m16) * 72 + ks * 32 + quad * 8];
#pragma unroll
      for (int nt = 0; nt < 4; nt++) {
        int dh = nt * 16 + m16;
        bf16x8 vf =
            *(const bf16x8*)&Vsb[dh * 64 + (((ks * 4 + quad) ^ sw) * 8)];
        o[0][nt] = MFMA16(pf0, vf, o[0][nt], 0, 0, 0);
        o[1][nt] = MFMA16(pf1, vf, o[1][nt], 0, 0, 0);
      }
    }
    S_BARRIER();  // all waves done reading buf cur; next iter may overwrite
  }

  // ---- deferred row-sum reduction across the 16 key-lanes
#pragma unroll
  for (int off = 1; off < 16; off <<= 1)
#pragma unroll
    for (int a = 0; a < 2; a++)
#pragma unroll
      for (int r = 0; r < 4; r++) rsum[a][r] += __shfl_xor(rsum[a][r], off);
#pragma unroll
  for (int a = 0; a < 2; a++)
#pragma unroll
    for (int r = 0; r < 4; r++) rsum[a][r] = 1.0f / rsum[a][r];

  // ---- epilogue: normalize, merge heads into ctx [B,S,D]
#pragma unroll
  for (int a = 0; a < 2; a++)
#pragma unroll
    for (int nt = 0; nt < 4; nt++) {
      int dh = nt * 16 + m16;
#pragma unroll
      for (int r = 0; r < 4; r++) {
        int sr = qt * 256 + w * 32 + a * 16 + quad * 4 + r;
        ctx[((size_t)(b * 2048 + sr)) * 1024 + h * 64 + dh] =
            (bf16)(o[a][nt][r] * rsum[a][r]);
      }
    }
}

// ---------------------------------------------------------------------------
extern "C" void kernel_launch(void* const* d_in, const int* in_sizes, int n_in,
                              void* d_out, int out_size, void* d_ws,
                              size_t ws_size, hipStream_t stream) {
  const float* key = (const float*)d_in[0];
  const float* query = (const float*)d_in[1];
  const float* value = (const float*)d_in[2];
  const int* vlen = (const int*)d_in[3];
  const float* Wk = (const float*)d_in[4];
  const float* Wq = (const float*)d_in[5];
  const float* Wv = (const float*)d_in[6];
  const float* Wo = (const float*)d_in[7];

  const size_t NE = (size_t)4 * 2048 * 1024;  // 8,388,608 elems per tensor
  const size_t WE = 1048576;                  // weight elems

  const size_t needA = (6 * NE + 4 * WE) * sizeof(bf16);  // ~109.1 MB
  const size_t needB = (5 * NE + 4 * WE) * sizeof(bf16);  // ~92.3 MB
  dim3 gg(4, 64), gb(512), cb(256), ag(8, 64), ab(512);

  if (ws_size >= needA) {
    // Tier A: separate activation buffers, fused QKV, vl-skip, fine tiles.
    bf16* qp = (bf16*)d_ws;
    bf16* kp = qp + NE;
    bf16* vt = kp + NE;
    bf16* xq = vt + NE;
    bf16* xk = xq + NE;
    bf16* xv = xk + NE;
    bf16* wb = xv + NE;
    bf16* ctx = xq;  // xq dead after gemm_qkv; reuse for attention output

    cvt4<<<dim3(1024, 4), cb, 0, stream>>>(Wq, Wk, Wv, Wo, wb);
    cvt3<<<dim3(8192, 3), cb, 0, stream>>>(query, key, value, xq, xk, xv);
    gemm_qkv<<<dim3(4, 64, 3), gb, 0, stream>>>(xq, xk, xv, wb, vlen, qp, kp,
                                                vt);
    attn<<<ag, ab, 0, stream>>>(qp, kp, vt, vlen, ctx);
    gemm_one<<<gg, gb, 0, stream>>>(ctx, wb + 3 * WE, d_out, 0);
  } else if (ws_size >= needB) {
    // Tier B: single reused activation buffer.
    bf16* qp = (bf16*)d_ws;
    bf16* kp = qp + NE;
    bf16* vt = kp + NE;
    bf16* ctx = vt + NE;
    bf16* xb = ctx + NE;
    bf16* wb = xb + NE;

    cvt4<<<dim3(1024, 4), cb, 0, stream>>>(Wq, Wk, Wv, Wo, wb);
    cvt1<<<8192, cb, 0, stream>>>(query, xb);
    gemm_one<<<gg, gb, 0, stream>>>(xb, wb + 0 * WE, qp, 1);
    cvt1<<<8192, cb, 0, stream>>>(key, xb);
    gemm_one<<<gg, gb, 0, stream>>>(xb, wb + 1 * WE, kp, 1);
    cvt1<<<8192, cb, 0, stream>>>(value, xb);
    gemm_one<<<gg, gb, 0, stream>>>(xb, wb + 2 * WE, vt, 2);
    attn<<<ag, ab, 0, stream>>>(qp, kp, vt, vlen, ctx);
    gemm_one<<<gg, gb, 0, stream>>>(ctx, wb + 3 * WE, d_out, 0);
  } else {
    // Tier C: fp32 staging inside GEMM.
    bf16* qp = (bf16*)d_ws;
    bf16* kp = qp + NE;
    bf16* vt = kp + NE;
    bf16* ctx = vt + NE;
    dim3 g8(8, 64), b256(256);
    gemm_bt<1, 1><<<g8, b256, 0, stream>>>(query, Wq, qp, 1);
    gemm_bt<1, 1><<<g8, b256, 0, stream>>>(key, Wk, kp, 1);
    gemm_bt<1, 1><<<g8, b256, 0, stream>>>(value, Wv, vt, 2);
    attn<<<ag, ab, 0, stream>>>(qp, kp, vt, vlen, ctx);
    gemm_bt<0, 1><<<g8, b256, 0, stream>>>(ctx, Wo, d_out, 0);
  }
}